// Round 2
// baseline (1536.834 us; speedup 1.0000x reference)
//
#include <hip/hip_runtime.h>
#include <hip/hip_bf16.h>

#define LK 0.01f
__device__ __forceinline__ float lrelu(float x){ return x >= 0.f ? x : LK * x; }

// Problem dims
#define NB 2
#define CMS 8       // band_ms
#define CHS 128     // band_hs
#define HW 512
#define HSIN 128    // hsi spatial
#define OS 32       // q/k spatial
#define K72 72      // 8 ch * 9 taps

// Workspace layout (float offsets). Total ~4.64M floats = 18.6 MB.
#define OFF_V   0                        // v fp32 [2][8][512][512]
#define SZ_V    (NB*CMS*HW*HW)
#define OFF_Q   (OFF_V + SZ_V)           // q fp32 [2][8][32][32]
#define SZ_Q    (NB*CMS*OS*OS)
#define OFF_K   (OFF_Q + SZ_Q)           // k fp32 [2][128][32][32]
#define SZ_K    (NB*CHS*OS*OS)
#define OFF_BN  (OFF_K + SZ_K)           // band norms [16] (pad 64)
#define OFF_AR  (OFF_BN + 64)            // att raw [2][8][128]
#define SZ_AR   (NB*CMS*CHS)
#define OFF_A2  (OFF_AR + SZ_AR)         // att softmaxed/6 [2][8][128]
#define OFF_WE  (OFF_A2 + SZ_AR)         // WeffT fp32 [n][72][128]
#define SZ_WE   (NB*K72*CHS)
#define OFF_WKT (OFF_WE + SZ_WE)         // Wk transposed fp32 [1152][128]
#define SZ_WKT  (1152*CHS)
#define OFF_WVT (OFF_WKT + SZ_WKT)       // Wv transposed fp32 [72][8]
#define SZ_WVT  (K72*CMS)

// ---------------- prep: transpose Wk and Wv to k-major ----------------
__global__ void prep_kernel(const float* __restrict__ Wk, const float* __restrict__ Wv,
                            float* __restrict__ wkt, float* __restrict__ wvT){
  int idx = blockIdx.x * 256 + threadIdx.x;
  if (idx < 147456){
    int co = idx & 127, kk = idx >> 7;
    wkt[kk*128 + co] = Wk[co*1152 + kk];
  } else if (idx < 147456 + 576){
    int l = idx - 147456;
    int co = l & 7, kt = l >> 3;
    wvT[kt*8 + co] = Wv[co*72 + kt];
  }
}

// ---------------- conv_v: 3x3 s1 p1, 8->8, lrelu, fp32 out ----------------
__global__ __launch_bounds__(256, 4)
void conv_v_kernel(const float* __restrict__ hrms, const float* __restrict__ wvT,
                   const float* __restrict__ bv, float* __restrict__ v){
  __shared__ float vt[CMS][34][36];
  __shared__ __align__(16) float wl[K72*CMS];   // 576 floats, [k][co]
  __shared__ float bvs[CMS];
  int xt = blockIdx.x, yt = blockIdx.y, n = blockIdx.z;
  int tid = threadIdx.x;
  for (int l = tid; l < CMS*34*34; l += 256){
    int ci = l / 1156, r = l % 1156, yy = r / 34, xx = r % 34;
    int gy = yt*32 + yy - 1, gx = xt*32 + xx - 1;
    float val = 0.f;
    if ((unsigned)gy < HW && (unsigned)gx < HW)
      val = hrms[((n*CMS+ci)*HW + gy)*HW + gx];
    vt[ci][yy][xx] = val;
  }
  for (int l = tid; l < K72*CMS; l += 256) wl[l] = wvT[l];
  if (tid < CMS) bvs[tid] = bv[tid];
  __syncthreads();
  int wid = tid >> 6;
  int lane = tid & 63;
  int lrow = lane >> 5, lx = lane & 31;
  for (int s = wid; s < 16; s += 4){                   // 16 strips of 2 rows
    int r0 = s*2 + lrow;
    float acc[8];
    #pragma unroll
    for (int c = 0; c < 8; c++) acc[c] = 0.f;
    #pragma unroll
    for (int ci = 0; ci < 8; ci++){
      float vv[9];
      #pragma unroll
      for (int t = 0; t < 9; t++) vv[t] = vt[ci][r0 + t/3][lx + t%3];
      #pragma unroll
      for (int tap = 0; tap < 9; tap++){
        const float4* wp = (const float4*)&wl[(ci*9 + tap)*8];
        float4 w0 = wp[0], w1 = wp[1];
        float vvt = vv[tap];
        acc[0] += w0.x*vvt; acc[1] += w0.y*vvt; acc[2] += w0.z*vvt; acc[3] += w0.w*vvt;
        acc[4] += w1.x*vvt; acc[5] += w1.y*vvt; acc[6] += w1.z*vvt; acc[7] += w1.w*vvt;
      }
    }
    int gy = yt*32 + r0, gx = xt*32 + lx;
    #pragma unroll
    for (int c = 0; c < 8; c++)
      v[((n*CMS+c)*HW + gy)*HW + gx] = lrelu(acc[c] + bvs[c]);
  }
}

// ---------------- conv_q: 3x3 stride 16 p1, 8->8, lrelu ----------------
__global__ void conv_q_kernel(const float* __restrict__ msi, const float* __restrict__ Wq,
                              const float* __restrict__ bq, float* __restrict__ q){
  __shared__ float rows[CMS][3][512];
  __shared__ float wq[K72*CMS];
  __shared__ float bqs[CMS];
  int n = blockIdx.x >> 5, y = blockIdx.x & 31;
  int tid = threadIdx.x;
  int y0 = y*16 - 1;
  for (int l = tid; l < CMS*3*512; l += 256){
    int ci = l / 1536, r = l % 1536, rr = r >> 9, xx = r & 511;
    int gy = y0 + rr;
    float val = 0.f;
    if ((unsigned)gy < HW) val = msi[((n*CMS+ci)*HW + gy)*HW + xx];
    rows[ci][rr][xx] = val;
  }
  for (int l = tid; l < K72*CMS; l += 256) wq[l] = Wq[l];   // [co][ci*9+tap]
  if (tid < CMS) bqs[tid] = bq[tid];
  __syncthreads();
  int x = tid & 31, co = tid >> 5;
  int x0 = x*16 - 1;
  float acc = bqs[co];
  #pragma unroll
  for (int ci = 0; ci < 8; ci++){
    #pragma unroll
    for (int tap = 0; tap < 9; tap++){
      int xi = x0 + tap%3;
      float vv = ((unsigned)xi < HW) ? rows[ci][tap/3][xi] : 0.f;
      acc += vv * wq[co*72 + ci*9 + tap];
    }
  }
  q[((n*CMS+co)*OS + y)*OS + x] = lrelu(acc);
}

// ---------------- per-band L2 norms of q ----------------
__global__ void bandnorm_kernel(const float* __restrict__ q, float* __restrict__ bn){
  int b = blockIdx.x;                 // n*8+i, 16 blocks
  int tid = threadIdx.x;              // 256
  const float* qb = q + b*1024;
  float s = 0.f;
  for (int j = tid; j < 1024; j += 256){ float v = qb[j]; s += v*v; }
  __shared__ float red[4];
  for (int off = 32; off; off >>= 1) s += __shfl_down(s, off);
  if ((tid & 63) == 0) red[tid >> 6] = s;
  __syncthreads();
  if (tid == 0) bn[b] = sqrtf(red[0] + red[1] + red[2] + red[3]);
}

// ---------------- conv_k: 3x3 stride 4 p1, 128->128, lrelu ----------------
__global__ void conv_k_kernel(const float* __restrict__ hsi, const float* __restrict__ wkt,
                              const float* __restrict__ bk, float* __restrict__ kw){
  __shared__ __align__(16) float patch[1152][4];
  int xg = blockIdx.x, y = blockIdx.y, n = blockIdx.z;
  int tid = threadIdx.x;
  for (int l = tid; l < 4608; l += 128){
    int kk = l >> 2, xi = l & 3;
    int ci = kk / 9, tap = kk % 9;
    int gy = 4*y + tap/3 - 1, gx = 4*(xg*4 + xi) + tap%3 - 1;
    float val = 0.f;
    if ((unsigned)gy < HSIN && (unsigned)gx < HSIN)
      val = hsi[((n*CHS+ci)*HSIN + gy)*HSIN + gx];
    patch[kk][xi] = val;
  }
  __syncthreads();
  int co = tid;
  float bkv = bk[co];
  float a0 = bkv, a1 = bkv, a2 = bkv, a3 = bkv;
  #pragma unroll 8
  for (int kk = 0; kk < 1152; kk++){
    float4 p = *(const float4*)patch[kk];   // broadcast b128
    float w = wkt[kk*128 + co];             // coalesced, L2-hot
    a0 += p.x * w; a1 += p.y * w; a2 += p.z * w; a3 += p.w * w;
  }
  int base = ((n*CHS + co)*OS + y)*OS + xg*4;
  kw[base + 0] = lrelu(a0); kw[base + 1] = lrelu(a1);
  kw[base + 2] = lrelu(a2); kw[base + 3] = lrelu(a3);
}

// ---------------- attention scores: ar[n,i,c] = <q_i, k_c>/k0max ----------------
__global__ void att_kernel(const float* __restrict__ q, const float* __restrict__ kw,
                           const float* __restrict__ bn, float* __restrict__ ar){
  int n = blockIdx.x >> 7, c = blockIdx.x & 127;
  int tid = threadIdx.x;   // 128
  const float* kb = kw + (n*CHS + c)*1024;
  float kreg[8];
  #pragma unroll
  for (int u = 0; u < 8; u++) kreg[u] = kb[tid + u*128];
  float m = bn[n*8];
  #pragma unroll
  for (int i = 1; i < 8; i++) m = fmaxf(m, bn[n*8 + i]);
  __shared__ float red[2];
  for (int i = 0; i < 8; i++){
    const float* qb = q + (n*CMS + i)*1024;
    float s = 0.f;
    #pragma unroll
    for (int u = 0; u < 8; u++) s += qb[tid + u*128] * kreg[u];
    for (int off = 32; off; off >>= 1) s += __shfl_down(s, off);
    if ((tid & 63) == 0) red[tid >> 6] = s;
    __syncthreads();
    if (tid == 0) ar[(n*CMS + i)*CHS + c] = (red[0] + red[1]) / m;
    __syncthreads();
  }
}

// ---------------- softmax over c (scale 10), then /6 ----------------
__global__ void softmax_kernel(const float* __restrict__ ar, float* __restrict__ a2){
  int b = blockIdx.x;      // n*8+i, 16 blocks
  int tid = threadIdx.x;   // 128 = c
  float x = ar[b*128 + tid] * 10.f;
  __shared__ float red[2];
  float m = x;
  for (int off = 32; off; off >>= 1) m = fmaxf(m, __shfl_xor(m, off));
  if ((tid & 63) == 0) red[tid >> 6] = m;
  __syncthreads();
  m = fmaxf(red[0], red[1]);
  float e = expf(x - m);
  float s = e;
  for (int off = 32; off; off >>= 1) s += __shfl_xor(s, off);
  __syncthreads();
  if ((tid & 63) == 0) red[tid >> 6] = s;
  __syncthreads();
  s = red[0] + red[1];
  a2[b*128 + tid] = e / (6.f * s);
}

// ---------------- Weff: weT[n][i*9+tap][o] = sum_c Wr[o,c,tap]*a2[n,i,c] ----------------
__global__ void weff_kernel(const float* __restrict__ Wr, const float* __restrict__ a2,
                            float* __restrict__ weT){
  int o = blockIdx.x & 127, n = blockIdx.x >> 7;
  int t = threadIdx.x;     // 128, first 72 active
  if (t >= 72) return;
  int i = t / 9, tap = t % 9;
  const float* av = a2 + (n*CMS + i)*CHS;
  float s = 0.f;
  for (int c = 0; c < 128; c++)
    s += Wr[(o*128 + c)*9 + tap] * av[c];
  weT[(n*K72 + t)*CHS + o] = s;
}

// ---------------- final: res = lrelu(conv3x3_{Weff[n]}(v) + br), fp32 out ----------------
// Block = (xt,yt,n): 32x32 pixels x 128 o. 512 threads (8 waves).
// Each lane processes TWO pixel rows (P=2) so every uniform ds_read_b128 of
// weights feeds 32 FMAs (DS pipe no longer the limit). Each wave owns rows
// 4*wid..4*wid+3 of the tile. Weights (72x128 = 36 KB) staged in LDS,
// broadcast-read. __launch_bounds__(512,2): 2 blocks/CU (LDS-capped anyway)
// -> 128-VGPR budget, so the ~90-reg live set does NOT spill to scratch
// (the round-1 (512,4) bound capped VGPRs at 64 and spilled ~3 GB of HBM
// scratch traffic).
__global__ __launch_bounds__(512, 2)
void final_kernel(const float* __restrict__ v, const float* __restrict__ weT,
                  const float* __restrict__ br, float* __restrict__ out){
  __shared__ float vt[CMS][34][36];
  __shared__ __align__(16) float wl[K72*CHS];   // 36,864 B  [k][o]
  __shared__ float brs[CHS];
  int xt = blockIdx.x, yt = blockIdx.y, n = blockIdx.z;
  int tid = threadIdx.x;
  for (int l = tid; l < CMS*34*34; l += 512){
    int i = l / 1156, r = l % 1156, yy = r / 34, xx = r % 34;
    int gy = yt*32 + yy - 1, gx = xt*32 + xx - 1;
    float val = 0.f;
    if ((unsigned)gy < HW && (unsigned)gx < HW)
      val = v[((n*CMS+i)*HW + gy)*HW + gx];
    vt[i][yy][xx] = val;
  }
  for (int l = tid; l < K72*CHS; l += 512) wl[l] = weT[n*K72*CHS + l];
  if (tid < CHS) brs[tid] = br[tid];
  __syncthreads();
  int wid = tid >> 6;        // 8 waves
  int lane = tid & 63;
  int lrow = lane >> 5, lx = lane & 31;
  int ra = 4*wid + lrow;     // pixel row A in tile
  int rb = ra + 2;           // pixel row B
  int gyA = yt*32 + ra, gyB = yt*32 + rb, gx = xt*32 + lx;
  for (int oc = 0; oc < 8; oc++){      // 16 o per chunk
    float accA[16], accB[16];
    #pragma unroll
    for (int j = 0; j < 16; j++){ accA[j] = 0.f; accB[j] = 0.f; }
    #pragma unroll
    for (int i = 0; i < 8; i++){
      #pragma unroll
      for (int tap = 0; tap < 9; tap++){
        float va = vt[i][ra + tap/3][lx + tap%3];
        float vb = vt[i][rb + tap/3][lx + tap%3];
        const float4* wp = (const float4*)&wl[(i*9 + tap)*CHS + oc*16];
        float4 w0 = wp[0], w1 = wp[1], w2 = wp[2], w3 = wp[3];
        accA[0]  += w0.x*va; accA[1]  += w0.y*va; accA[2]  += w0.z*va; accA[3]  += w0.w*va;
        accA[4]  += w1.x*va; accA[5]  += w1.y*va; accA[6]  += w1.z*va; accA[7]  += w1.w*va;
        accA[8]  += w2.x*va; accA[9]  += w2.y*va; accA[10] += w2.z*va; accA[11] += w2.w*va;
        accA[12] += w3.x*va; accA[13] += w3.y*va; accA[14] += w3.z*va; accA[15] += w3.w*va;
        accB[0]  += w0.x*vb; accB[1]  += w0.y*vb; accB[2]  += w0.z*vb; accB[3]  += w0.w*vb;
        accB[4]  += w1.x*vb; accB[5]  += w1.y*vb; accB[6]  += w1.z*vb; accB[7]  += w1.w*vb;
        accB[8]  += w2.x*vb; accB[9]  += w2.y*vb; accB[10] += w2.z*vb; accB[11] += w2.w*vb;
        accB[12] += w3.x*vb; accB[13] += w3.y*vb; accB[14] += w3.z*vb; accB[15] += w3.w*vb;
      }
    }
    int obase = oc*16;
    #pragma unroll
    for (int j = 0; j < 16; j++){
      int o = obase + j;
      float b = brs[o];
      out[((n*CHS + o)*HW + gyA)*HW + gx] = lrelu(accA[j] + b);
      out[((n*CHS + o)*HW + gyB)*HW + gx] = lrelu(accB[j] + b);
    }
  }
}

extern "C" void kernel_launch(void* const* d_in, const int* in_sizes, int n_in,
                              void* d_out, int out_size, void* d_ws, size_t ws_size,
                              hipStream_t stream){
  const float* hrms = (const float*)d_in[0];
  const float* msi  = (const float*)d_in[1];
  const float* hsi  = (const float*)d_in[2];
  const float* Wv   = (const float*)d_in[3];
  const float* bv   = (const float*)d_in[4];
  const float* Wq   = (const float*)d_in[5];
  const float* bq   = (const float*)d_in[6];
  const float* Wk   = (const float*)d_in[7];
  const float* bk   = (const float*)d_in[8];
  const float* Wr   = (const float*)d_in[9];
  const float* br   = (const float*)d_in[10];
  float* ws = (float*)d_ws;
  float* out = (float*)d_out;

  float* v   = ws + OFF_V;
  float* q   = ws + OFF_Q;
  float* kw  = ws + OFF_K;
  float* bn  = ws + OFF_BN;
  float* ar  = ws + OFF_AR;
  float* a2  = ws + OFF_A2;
  float* weT = ws + OFF_WE;
  float* wkt = ws + OFF_WKT;
  float* wvT = ws + OFF_WVT;

  hipLaunchKernelGGL(prep_kernel, dim3(579), dim3(256), 0, stream, Wk, Wv, wkt, wvT);
  hipLaunchKernelGGL(conv_v_kernel, dim3(16,16,2), dim3(256), 0, stream, hrms, wvT, bv, v);
  hipLaunchKernelGGL(conv_q_kernel, dim3(64), dim3(256), 0, stream, msi, Wq, bq, q);
  hipLaunchKernelGGL(bandnorm_kernel, dim3(16), dim3(256), 0, stream, q, bn);
  hipLaunchKernelGGL(conv_k_kernel, dim3(8,32,2), dim3(128), 0, stream, hsi, wkt, bk, kw);
  hipLaunchKernelGGL(att_kernel, dim3(256), dim3(128), 0, stream, q, kw, bn, ar);
  hipLaunchKernelGGL(softmax_kernel, dim3(16), dim3(128), 0, stream, ar, a2);
  hipLaunchKernelGGL(weff_kernel, dim3(256), dim3(128), 0, stream, Wr, a2, weT);
  hipLaunchKernelGGL(final_kernel, dim3(16,16,2), dim3(512), 0, stream, v, weT, br, out);
}

// Round 3
// 749.748 us; speedup vs baseline: 2.0498x; 2.0498x over previous
//
#include <hip/hip_runtime.h>
#include <hip/hip_bf16.h>

#define LK 0.01f
__device__ __forceinline__ float lrelu(float x){ return x >= 0.f ? x : LK * x; }

// Problem dims
#define NB 2
#define CMS 8       // band_ms
#define CHS 128     // band_hs
#define HW 512
#define HSIN 128    // hsi spatial
#define OS 32       // q/k spatial
#define K72 72      // 8 ch * 9 taps

// Workspace layout (float offsets). Total ~4.64M floats = 18.6 MB.
#define OFF_V   0                        // v fp32 [2][8][512][512]
#define SZ_V    (NB*CMS*HW*HW)
#define OFF_Q   (OFF_V + SZ_V)           // q fp32 [2][8][32][32]
#define SZ_Q    (NB*CMS*OS*OS)
#define OFF_K   (OFF_Q + SZ_Q)           // k fp32 [2][128][32][32]
#define SZ_K    (NB*CHS*OS*OS)
#define OFF_BN  (OFF_K + SZ_K)           // band norms [16] (pad 64)
#define OFF_AR  (OFF_BN + 64)            // att raw [2][8][128]
#define SZ_AR   (NB*CMS*CHS)
#define OFF_A2  (OFF_AR + SZ_AR)         // att softmaxed/6 [2][8][128]
#define OFF_WE  (OFF_A2 + SZ_AR)         // WeffT fp32 [n][72][128]
#define SZ_WE   (NB*K72*CHS)
#define OFF_WKT (OFF_WE + SZ_WE)         // Wk transposed fp32 [1152][128]
#define SZ_WKT  (1152*CHS)
#define OFF_WVT (OFF_WKT + SZ_WKT)       // Wv transposed fp32 [72][8]
#define SZ_WVT  (K72*CMS)

// ---------------- prep: transpose Wk and Wv to k-major ----------------
__global__ void prep_kernel(const float* __restrict__ Wk, const float* __restrict__ Wv,
                            float* __restrict__ wkt, float* __restrict__ wvT){
  int idx = blockIdx.x * 256 + threadIdx.x;
  if (idx < 147456){
    int co = idx & 127, kk = idx >> 7;
    wkt[kk*128 + co] = Wk[co*1152 + kk];
  } else if (idx < 147456 + 576){
    int l = idx - 147456;
    int co = l & 7, kt = l >> 3;
    wvT[kt*8 + co] = Wv[co*72 + kt];
  }
}

// ---------------- conv_v: 3x3 s1 p1, 8->8, lrelu, fp32 out ----------------
__global__ __launch_bounds__(256, 4)
void conv_v_kernel(const float* __restrict__ hrms, const float* __restrict__ wvT,
                   const float* __restrict__ bv, float* __restrict__ v){
  __shared__ float vt[CMS][34][36];
  __shared__ __align__(16) float wl[K72*CMS];   // 576 floats, [k][co]
  __shared__ float bvs[CMS];
  int xt = blockIdx.x, yt = blockIdx.y, n = blockIdx.z;
  int tid = threadIdx.x;
  for (int l = tid; l < CMS*34*34; l += 256){
    int ci = l / 1156, r = l % 1156, yy = r / 34, xx = r % 34;
    int gy = yt*32 + yy - 1, gx = xt*32 + xx - 1;
    float val = 0.f;
    if ((unsigned)gy < HW && (unsigned)gx < HW)
      val = hrms[((n*CMS+ci)*HW + gy)*HW + gx];
    vt[ci][yy][xx] = val;
  }
  for (int l = tid; l < K72*CMS; l += 256) wl[l] = wvT[l];
  if (tid < CMS) bvs[tid] = bv[tid];
  __syncthreads();
  int wid = tid >> 6;
  int lane = tid & 63;
  int lrow = lane >> 5, lx = lane & 31;
  for (int s = wid; s < 16; s += 4){                   // 16 strips of 2 rows
    int r0 = s*2 + lrow;
    float acc[8];
    #pragma unroll
    for (int c = 0; c < 8; c++) acc[c] = 0.f;
    #pragma unroll
    for (int ci = 0; ci < 8; ci++){
      float vv[9];
      #pragma unroll
      for (int t = 0; t < 9; t++) vv[t] = vt[ci][r0 + t/3][lx + t%3];
      #pragma unroll
      for (int tap = 0; tap < 9; tap++){
        const float4* wp = (const float4*)&wl[(ci*9 + tap)*8];
        float4 w0 = wp[0], w1 = wp[1];
        float vvt = vv[tap];
        acc[0] += w0.x*vvt; acc[1] += w0.y*vvt; acc[2] += w0.z*vvt; acc[3] += w0.w*vvt;
        acc[4] += w1.x*vvt; acc[5] += w1.y*vvt; acc[6] += w1.z*vvt; acc[7] += w1.w*vvt;
      }
    }
    int gy = yt*32 + r0, gx = xt*32 + lx;
    #pragma unroll
    for (int c = 0; c < 8; c++)
      v[((n*CMS+c)*HW + gy)*HW + gx] = lrelu(acc[c] + bvs[c]);
  }
}

// ---------------- conv_q: 3x3 stride 16 p1, 8->8, lrelu ----------------
__global__ void conv_q_kernel(const float* __restrict__ msi, const float* __restrict__ Wq,
                              const float* __restrict__ bq, float* __restrict__ q){
  __shared__ float rows[CMS][3][512];
  __shared__ float wq[K72*CMS];
  __shared__ float bqs[CMS];
  int n = blockIdx.x >> 5, y = blockIdx.x & 31;
  int tid = threadIdx.x;
  int y0 = y*16 - 1;
  for (int l = tid; l < CMS*3*512; l += 256){
    int ci = l / 1536, r = l % 1536, rr = r >> 9, xx = r & 511;
    int gy = y0 + rr;
    float val = 0.f;
    if ((unsigned)gy < HW) val = msi[((n*CMS+ci)*HW + gy)*HW + xx];
    rows[ci][rr][xx] = val;
  }
  for (int l = tid; l < K72*CMS; l += 256) wq[l] = Wq[l];   // [co][ci*9+tap]
  if (tid < CMS) bqs[tid] = bq[tid];
  __syncthreads();
  int x = tid & 31, co = tid >> 5;
  int x0 = x*16 - 1;
  float acc = bqs[co];
  #pragma unroll
  for (int ci = 0; ci < 8; ci++){
    #pragma unroll
    for (int tap = 0; tap < 9; tap++){
      int xi = x0 + tap%3;
      float vv = ((unsigned)xi < HW) ? rows[ci][tap/3][xi] : 0.f;
      acc += vv * wq[co*72 + ci*9 + tap];
    }
  }
  q[((n*CMS+co)*OS + y)*OS + x] = lrelu(acc);
}

// ---------------- per-band L2 norms of q ----------------
__global__ void bandnorm_kernel(const float* __restrict__ q, float* __restrict__ bn){
  int b = blockIdx.x;                 // n*8+i, 16 blocks
  int tid = threadIdx.x;              // 256
  const float* qb = q + b*1024;
  float s = 0.f;
  for (int j = tid; j < 1024; j += 256){ float v = qb[j]; s += v*v; }
  __shared__ float red[4];
  for (int off = 32; off; off >>= 1) s += __shfl_down(s, off);
  if ((tid & 63) == 0) red[tid >> 6] = s;
  __syncthreads();
  if (tid == 0) bn[b] = sqrtf(red[0] + red[1] + red[2] + red[3]);
}

// ---------------- conv_k: 3x3 stride 4 p1, 128->128, lrelu ----------------
__global__ void conv_k_kernel(const float* __restrict__ hsi, const float* __restrict__ wkt,
                              const float* __restrict__ bk, float* __restrict__ kw){
  __shared__ __align__(16) float patch[1152][4];
  int xg = blockIdx.x, y = blockIdx.y, n = blockIdx.z;
  int tid = threadIdx.x;
  for (int l = tid; l < 4608; l += 128){
    int kk = l >> 2, xi = l & 3;
    int ci = kk / 9, tap = kk % 9;
    int gy = 4*y + tap/3 - 1, gx = 4*(xg*4 + xi) + tap%3 - 1;
    float val = 0.f;
    if ((unsigned)gy < HSIN && (unsigned)gx < HSIN)
      val = hsi[((n*CHS+ci)*HSIN + gy)*HSIN + gx];
    patch[kk][xi] = val;
  }
  __syncthreads();
  int co = tid;
  float bkv = bk[co];
  float a0 = bkv, a1 = bkv, a2 = bkv, a3 = bkv;
  #pragma unroll 8
  for (int kk = 0; kk < 1152; kk++){
    float4 p = *(const float4*)patch[kk];   // broadcast b128
    float w = wkt[kk*128 + co];             // coalesced, L2-hot
    a0 += p.x * w; a1 += p.y * w; a2 += p.z * w; a3 += p.w * w;
  }
  int base = ((n*CHS + co)*OS + y)*OS + xg*4;
  kw[base + 0] = lrelu(a0); kw[base + 1] = lrelu(a1);
  kw[base + 2] = lrelu(a2); kw[base + 3] = lrelu(a3);
}

// ---------------- attention scores: ar[n,i,c] = <q_i, k_c>/k0max ----------------
__global__ void att_kernel(const float* __restrict__ q, const float* __restrict__ kw,
                           const float* __restrict__ bn, float* __restrict__ ar){
  int n = blockIdx.x >> 7, c = blockIdx.x & 127;
  int tid = threadIdx.x;   // 128
  const float* kb = kw + (n*CHS + c)*1024;
  float kreg[8];
  #pragma unroll
  for (int u = 0; u < 8; u++) kreg[u] = kb[tid + u*128];
  float m = bn[n*8];
  #pragma unroll
  for (int i = 1; i < 8; i++) m = fmaxf(m, bn[n*8 + i]);
  __shared__ float red[2];
  for (int i = 0; i < 8; i++){
    const float* qb = q + (n*CMS + i)*1024;
    float s = 0.f;
    #pragma unroll
    for (int u = 0; u < 8; u++) s += qb[tid + u*128] * kreg[u];
    for (int off = 32; off; off >>= 1) s += __shfl_down(s, off);
    if ((tid & 63) == 0) red[tid >> 6] = s;
    __syncthreads();
    if (tid == 0) ar[(n*CMS + i)*CHS + c] = (red[0] + red[1]) / m;
    __syncthreads();
  }
}

// ---------------- softmax over c (scale 10), then /6 ----------------
__global__ void softmax_kernel(const float* __restrict__ ar, float* __restrict__ a2){
  int b = blockIdx.x;      // n*8+i, 16 blocks
  int tid = threadIdx.x;   // 128 = c
  float x = ar[b*128 + tid] * 10.f;
  __shared__ float red[2];
  float m = x;
  for (int off = 32; off; off >>= 1) m = fmaxf(m, __shfl_xor(m, off));
  if ((tid & 63) == 0) red[tid >> 6] = m;
  __syncthreads();
  m = fmaxf(red[0], red[1]);
  float e = expf(x - m);
  float s = e;
  for (int off = 32; off; off >>= 1) s += __shfl_xor(s, off);
  __syncthreads();
  if ((tid & 63) == 0) red[tid >> 6] = s;
  __syncthreads();
  s = red[0] + red[1];
  a2[b*128 + tid] = e / (6.f * s);
}

// ---------------- Weff: weT[n][i*9+tap][o] = sum_c Wr[o,c,tap]*a2[n,i,c] ----------------
__global__ void weff_kernel(const float* __restrict__ Wr, const float* __restrict__ a2,
                            float* __restrict__ weT){
  int o = blockIdx.x & 127, n = blockIdx.x >> 7;
  int t = threadIdx.x;     // 128, first 72 active
  if (t >= 72) return;
  int i = t / 9, tap = t % 9;
  const float* av = a2 + (n*CMS + i)*CHS;
  float s = 0.f;
  for (int c = 0; c < 128; c++)
    s += Wr[(o*128 + c)*9 + tap] * av[c];
  weT[(n*K72 + t)*CHS + o] = s;
}

// ---------------- final: res = lrelu(conv3x3_{Weff[n]}(v) + br), fp32 out ----------------
// ROW-BAND layout: block = (band of 4 rows, n), grid 256 = 1 block/CU.
// Lane = column (512 threads = 512 cols). Every wave store is 256 B
// contiguous; a block finishes full 2-KB output rows per o-plane in one
// burst (previous 32x32-tile layout wrote scattered 128-B segments at 1-MB
// plane stride -> fetch/write ~1.5 GB each, 960 us regardless of inner loop).
// v rows (8ch x 6 x 520, ~100 KB) + weights (36 KB) staged in LDS.
// Weights broadcast-read (uniform addr); v reads consecutive-col b32,
// conflict-free. Accumulation order (i outer, tap inner) identical to prior
// versions -> bit-identical output.
__global__ __launch_bounds__(512, 2)
void final_kernel(const float* __restrict__ v, const float* __restrict__ weT,
                  const float* __restrict__ br, float* __restrict__ out){
  __shared__ float vt[CMS][6][520];             // rows r0-1..r0+4, col+1 shift
  __shared__ __align__(16) float wl[K72*CHS];   // 36,864 B  [k][o]
  __shared__ float brs[CHS];
  int band = blockIdx.x, n = blockIdx.y;
  int tid = threadIdx.x;
  int r0 = band*4;
  for (int l = tid; l < CMS*6*512; l += 512){
    int i = l / 3072, rem = l - i*3072, r = rem >> 9, x = rem & 511;
    int gy = r0 - 1 + r;
    float val = 0.f;
    if ((unsigned)gy < HW) val = v[((n*CMS+i)*HW + gy)*HW + x];
    vt[i][r][x+1] = val;
  }
  if (tid < CMS*6){ int i = tid/6, r = tid - i*6; vt[i][r][0] = 0.f; vt[i][r][513] = 0.f; }
  for (int l = tid; l < K72*CHS; l += 512) wl[l] = weT[n*K72*CHS + l];
  if (tid < CHS) brs[tid] = br[tid];
  __syncthreads();
  int col = tid;   // 0..511
  for (int oc = 0; oc < 8; oc++){      // 16 o per chunk
    float acc[4][16];
    #pragma unroll
    for (int rr = 0; rr < 4; rr++)
      #pragma unroll
      for (int j = 0; j < 16; j++) acc[rr][j] = 0.f;
    #pragma unroll
    for (int i = 0; i < 8; i++){
      float vv[6][3];
      #pragma unroll
      for (int r = 0; r < 6; r++){
        #pragma unroll
        for (int dc = 0; dc < 3; dc++)
          vv[r][dc] = vt[i][r][col + dc];
      }
      #pragma unroll
      for (int dy = 0; dy < 3; dy++){
        #pragma unroll
        for (int dx = 0; dx < 3; dx++){
          const float4* wp = (const float4*)&wl[(i*9 + dy*3 + dx)*CHS + oc*16];
          float4 w0 = wp[0], w1 = wp[1], w2 = wp[2], w3 = wp[3];
          #pragma unroll
          for (int rr = 0; rr < 4; rr++){
            float va = vv[rr + dy][dx];
            acc[rr][0]  += w0.x*va; acc[rr][1]  += w0.y*va; acc[rr][2]  += w0.z*va; acc[rr][3]  += w0.w*va;
            acc[rr][4]  += w1.x*va; acc[rr][5]  += w1.y*va; acc[rr][6]  += w1.z*va; acc[rr][7]  += w1.w*va;
            acc[rr][8]  += w2.x*va; acc[rr][9]  += w2.y*va; acc[rr][10] += w2.z*va; acc[rr][11] += w2.w*va;
            acc[rr][12] += w3.x*va; acc[rr][13] += w3.y*va; acc[rr][14] += w3.z*va; acc[rr][15] += w3.w*va;
          }
        }
      }
    }
    #pragma unroll
    for (int j = 0; j < 16; j++){
      int o = oc*16 + j;
      float b = brs[o];
      #pragma unroll
      for (int rr = 0; rr < 4; rr++)
        out[((n*CHS + o)*HW + (r0 + rr))*HW + col] = lrelu(acc[rr][j] + b);
    }
  }
}

extern "C" void kernel_launch(void* const* d_in, const int* in_sizes, int n_in,
                              void* d_out, int out_size, void* d_ws, size_t ws_size,
                              hipStream_t stream){
  const float* hrms = (const float*)d_in[0];
  const float* msi  = (const float*)d_in[1];
  const float* hsi  = (const float*)d_in[2];
  const float* Wv   = (const float*)d_in[3];
  const float* bv   = (const float*)d_in[4];
  const float* Wq   = (const float*)d_in[5];
  const float* bq   = (const float*)d_in[6];
  const float* Wk   = (const float*)d_in[7];
  const float* bk   = (const float*)d_in[8];
  const float* Wr   = (const float*)d_in[9];
  const float* br   = (const float*)d_in[10];
  float* ws = (float*)d_ws;
  float* out = (float*)d_out;

  float* v   = ws + OFF_V;
  float* q   = ws + OFF_Q;
  float* kw  = ws + OFF_K;
  float* bn  = ws + OFF_BN;
  float* ar  = ws + OFF_AR;
  float* a2  = ws + OFF_A2;
  float* weT = ws + OFF_WE;
  float* wkt = ws + OFF_WKT;
  float* wvT = ws + OFF_WVT;

  hipLaunchKernelGGL(prep_kernel, dim3(579), dim3(256), 0, stream, Wk, Wv, wkt, wvT);
  hipLaunchKernelGGL(conv_v_kernel, dim3(16,16,2), dim3(256), 0, stream, hrms, wvT, bv, v);
  hipLaunchKernelGGL(conv_q_kernel, dim3(64), dim3(256), 0, stream, msi, Wq, bq, q);
  hipLaunchKernelGGL(bandnorm_kernel, dim3(16), dim3(256), 0, stream, q, bn);
  hipLaunchKernelGGL(conv_k_kernel, dim3(8,32,2), dim3(128), 0, stream, hsi, wkt, bk, kw);
  hipLaunchKernelGGL(att_kernel, dim3(256), dim3(128), 0, stream, q, kw, bn, ar);
  hipLaunchKernelGGL(softmax_kernel, dim3(16), dim3(128), 0, stream, ar, a2);
  hipLaunchKernelGGL(weff_kernel, dim3(256), dim3(128), 0, stream, Wr, a2, weT);
  hipLaunchKernelGGL(final_kernel, dim3(128, 2), dim3(512), 0, stream, v, weT, br, out);
}

// Round 4
// 590.974 us; speedup vs baseline: 2.6005x; 1.2687x over previous
//
#include <hip/hip_runtime.h>
#include <hip/hip_bf16.h>

#define LK 0.01f
__device__ __forceinline__ float lrelu(float x){ return x >= 0.f ? x : LK * x; }

// Problem dims
#define NB 2
#define CMS 8       // band_ms
#define CHS 128     // band_hs
#define HW 512
#define HSIN 128    // hsi spatial
#define OS 32       // q/k spatial
#define K72 72      // 8 ch * 9 taps

// Workspace layout (float offsets). Total ~4.64M floats = 18.6 MB.
#define OFF_V   0                        // v fp32 [2][8][512][512]
#define SZ_V    (NB*CMS*HW*HW)
#define OFF_Q   (OFF_V + SZ_V)           // q fp32 [2][8][32][32]
#define SZ_Q    (NB*CMS*OS*OS)
#define OFF_K   (OFF_Q + SZ_Q)           // k fp32 [2][128][32][32]
#define SZ_K    (NB*CHS*OS*OS)
#define OFF_BN  (OFF_K + SZ_K)           // band norms [16] (pad 64)
#define OFF_AR  (OFF_BN + 64)            // att raw [2][8][128]
#define SZ_AR   (NB*CMS*CHS)
#define OFF_A2  (OFF_AR + SZ_AR)         // att softmaxed/6 [2][8][128]
#define OFF_WE  (OFF_A2 + SZ_AR)         // WeffT fp32 [n][72][128]
#define SZ_WE   (NB*K72*CHS)
#define OFF_WKT (OFF_WE + SZ_WE)         // Wk transposed fp32 [1152][128]
#define SZ_WKT  (1152*CHS)
#define OFF_WVT (OFF_WKT + SZ_WKT)       // Wv transposed fp32 [72][8]
#define SZ_WVT  (K72*CMS)

// ---------------- prep: transpose Wk and Wv to k-major ----------------
__global__ void prep_kernel(const float* __restrict__ Wk, const float* __restrict__ Wv,
                            float* __restrict__ wkt, float* __restrict__ wvT){
  int idx = blockIdx.x * 256 + threadIdx.x;
  if (idx < 147456){
    int co = idx & 127, kk = idx >> 7;
    wkt[kk*128 + co] = Wk[co*1152 + kk];
  } else if (idx < 147456 + 576){
    int l = idx - 147456;
    int co = l & 7, kt = l >> 3;
    wvT[kt*8 + co] = Wv[co*72 + kt];
  }
}

// ---------------- conv_v: 3x3 s1 p1, 8->8, lrelu, fp32 out ----------------
__global__ __launch_bounds__(256, 4)
void conv_v_kernel(const float* __restrict__ hrms, const float* __restrict__ wvT,
                   const float* __restrict__ bv, float* __restrict__ v){
  __shared__ float vt[CMS][34][36];
  __shared__ __align__(16) float wl[K72*CMS];   // 576 floats, [k][co]
  __shared__ float bvs[CMS];
  int xt = blockIdx.x, yt = blockIdx.y, n = blockIdx.z;
  int tid = threadIdx.x;
  for (int l = tid; l < CMS*34*34; l += 256){
    int ci = l / 1156, r = l % 1156, yy = r / 34, xx = r % 34;
    int gy = yt*32 + yy - 1, gx = xt*32 + xx - 1;
    float val = 0.f;
    if ((unsigned)gy < HW && (unsigned)gx < HW)
      val = hrms[((n*CMS+ci)*HW + gy)*HW + gx];
    vt[ci][yy][xx] = val;
  }
  for (int l = tid; l < K72*CMS; l += 256) wl[l] = wvT[l];
  if (tid < CMS) bvs[tid] = bv[tid];
  __syncthreads();
  int wid = tid >> 6;
  int lane = tid & 63;
  int lrow = lane >> 5, lx = lane & 31;
  for (int s = wid; s < 16; s += 4){                   // 16 strips of 2 rows
    int r0 = s*2 + lrow;
    float acc[8];
    #pragma unroll
    for (int c = 0; c < 8; c++) acc[c] = 0.f;
    #pragma unroll
    for (int ci = 0; ci < 8; ci++){
      float vv[9];
      #pragma unroll
      for (int t = 0; t < 9; t++) vv[t] = vt[ci][r0 + t/3][lx + t%3];
      #pragma unroll
      for (int tap = 0; tap < 9; tap++){
        const float4* wp = (const float4*)&wl[(ci*9 + tap)*8];
        float4 w0 = wp[0], w1 = wp[1];
        float vvt = vv[tap];
        acc[0] += w0.x*vvt; acc[1] += w0.y*vvt; acc[2] += w0.z*vvt; acc[3] += w0.w*vvt;
        acc[4] += w1.x*vvt; acc[5] += w1.y*vvt; acc[6] += w1.z*vvt; acc[7] += w1.w*vvt;
      }
    }
    int gy = yt*32 + r0, gx = xt*32 + lx;
    #pragma unroll
    for (int c = 0; c < 8; c++)
      v[((n*CMS+c)*HW + gy)*HW + gx] = lrelu(acc[c] + bvs[c]);
  }
}

// ---------------- conv_q: 3x3 stride 16 p1, 8->8, lrelu ----------------
__global__ void conv_q_kernel(const float* __restrict__ msi, const float* __restrict__ Wq,
                              const float* __restrict__ bq, float* __restrict__ q){
  __shared__ float rows[CMS][3][512];
  __shared__ float wq[K72*CMS];
  __shared__ float bqs[CMS];
  int n = blockIdx.x >> 5, y = blockIdx.x & 31;
  int tid = threadIdx.x;
  int y0 = y*16 - 1;
  for (int l = tid; l < CMS*3*512; l += 256){
    int ci = l / 1536, r = l % 1536, rr = r >> 9, xx = r & 511;
    int gy = y0 + rr;
    float val = 0.f;
    if ((unsigned)gy < HW) val = msi[((n*CMS+ci)*HW + gy)*HW + xx];
    rows[ci][rr][xx] = val;
  }
  for (int l = tid; l < K72*CMS; l += 256) wq[l] = Wq[l];   // [co][ci*9+tap]
  if (tid < CMS) bqs[tid] = bq[tid];
  __syncthreads();
  int x = tid & 31, co = tid >> 5;
  int x0 = x*16 - 1;
  float acc = bqs[co];
  #pragma unroll
  for (int ci = 0; ci < 8; ci++){
    #pragma unroll
    for (int tap = 0; tap < 9; tap++){
      int xi = x0 + tap%3;
      float vv = ((unsigned)xi < HW) ? rows[ci][tap/3][xi] : 0.f;
      acc += vv * wq[co*72 + ci*9 + tap];
    }
  }
  q[((n*CMS+co)*OS + y)*OS + x] = lrelu(acc);
}

// ---------------- per-band L2 norms of q ----------------
__global__ void bandnorm_kernel(const float* __restrict__ q, float* __restrict__ bn){
  int b = blockIdx.x;                 // n*8+i, 16 blocks
  int tid = threadIdx.x;              // 256
  const float* qb = q + b*1024;
  float s = 0.f;
  for (int j = tid; j < 1024; j += 256){ float v = qb[j]; s += v*v; }
  __shared__ float red[4];
  for (int off = 32; off; off >>= 1) s += __shfl_down(s, off);
  if ((tid & 63) == 0) red[tid >> 6] = s;
  __syncthreads();
  if (tid == 0) bn[b] = sqrtf(red[0] + red[1] + red[2] + red[3]);
}

// ---------------- conv_k: 3x3 stride 4 p1, 128->128, lrelu ----------------
__global__ void conv_k_kernel(const float* __restrict__ hsi, const float* __restrict__ wkt,
                              const float* __restrict__ bk, float* __restrict__ kw){
  __shared__ __align__(16) float patch[1152][4];
  int xg = blockIdx.x, y = blockIdx.y, n = blockIdx.z;
  int tid = threadIdx.x;
  for (int l = tid; l < 4608; l += 128){
    int kk = l >> 2, xi = l & 3;
    int ci = kk / 9, tap = kk % 9;
    int gy = 4*y + tap/3 - 1, gx = 4*(xg*4 + xi) + tap%3 - 1;
    float val = 0.f;
    if ((unsigned)gy < HSIN && (unsigned)gx < HSIN)
      val = hsi[((n*CHS+ci)*HSIN + gy)*HSIN + gx];
    patch[kk][xi] = val;
  }
  __syncthreads();
  int co = tid;
  float bkv = bk[co];
  float a0 = bkv, a1 = bkv, a2 = bkv, a3 = bkv;
  #pragma unroll 8
  for (int kk = 0; kk < 1152; kk++){
    float4 p = *(const float4*)patch[kk];   // broadcast b128
    float w = wkt[kk*128 + co];             // coalesced, L2-hot
    a0 += p.x * w; a1 += p.y * w; a2 += p.z * w; a3 += p.w * w;
  }
  int base = ((n*CHS + co)*OS + y)*OS + xg*4;
  kw[base + 0] = lrelu(a0); kw[base + 1] = lrelu(a1);
  kw[base + 2] = lrelu(a2); kw[base + 3] = lrelu(a3);
}

// ---------------- attention scores: ar[n,i,c] = <q_i, k_c>/k0max ----------------
__global__ void att_kernel(const float* __restrict__ q, const float* __restrict__ kw,
                           const float* __restrict__ bn, float* __restrict__ ar){
  int n = blockIdx.x >> 7, c = blockIdx.x & 127;
  int tid = threadIdx.x;   // 128
  const float* kb = kw + (n*CHS + c)*1024;
  float kreg[8];
  #pragma unroll
  for (int u = 0; u < 8; u++) kreg[u] = kb[tid + u*128];
  float m = bn[n*8];
  #pragma unroll
  for (int i = 1; i < 8; i++) m = fmaxf(m, bn[n*8 + i]);
  __shared__ float red[2];
  for (int i = 0; i < 8; i++){
    const float* qb = q + (n*CMS + i)*1024;
    float s = 0.f;
    #pragma unroll
    for (int u = 0; u < 8; u++) s += qb[tid + u*128] * kreg[u];
    for (int off = 32; off; off >>= 1) s += __shfl_down(s, off);
    if ((tid & 63) == 0) red[tid >> 6] = s;
    __syncthreads();
    if (tid == 0) ar[(n*CMS + i)*CHS + c] = (red[0] + red[1]) / m;
    __syncthreads();
  }
}

// ---------------- softmax over c (scale 10), then /6 ----------------
__global__ void softmax_kernel(const float* __restrict__ ar, float* __restrict__ a2){
  int b = blockIdx.x;      // n*8+i, 16 blocks
  int tid = threadIdx.x;   // 128 = c
  float x = ar[b*128 + tid] * 10.f;
  __shared__ float red[2];
  float m = x;
  for (int off = 32; off; off >>= 1) m = fmaxf(m, __shfl_xor(m, off));
  if ((tid & 63) == 0) red[tid >> 6] = m;
  __syncthreads();
  m = fmaxf(red[0], red[1]);
  float e = expf(x - m);
  float s = e;
  for (int off = 32; off; off >>= 1) s += __shfl_xor(s, off);
  __syncthreads();
  if ((tid & 63) == 0) red[tid >> 6] = s;
  __syncthreads();
  s = red[0] + red[1];
  a2[b*128 + tid] = e / (6.f * s);
}

// ---------------- Weff: weT[n][i*9+tap][o] = sum_c Wr[o,c,tap]*a2[n,i,c] ----------------
__global__ void weff_kernel(const float* __restrict__ Wr, const float* __restrict__ a2,
                            float* __restrict__ weT){
  int o = blockIdx.x & 127, n = blockIdx.x >> 7;
  int t = threadIdx.x;     // 128, first 72 active
  if (t >= 72) return;
  int i = t / 9, tap = t % 9;
  const float* av = a2 + (n*CMS + i)*CHS;
  float s = 0.f;
  for (int c = 0; c < 128; c++)
    s += Wr[(o*128 + c)*9 + tap] * av[c];
  weT[(n*K72 + t)*CHS + o] = s;
}

// ---------------- final: res = lrelu(conv3x3_{Weff[n]}(v) + br), fp32 out ----------------
// Block = (band of 4 rows, n), grid 256 = 1 block/CU, 512 threads (8 waves).
// WAVE OWNS ONE o-CHUNK (16 o's): weight b128 reads per wave drop 2x vs the
// oc-loop layout, and each 4-b128 weight group now feeds 128 FMAs (2 col-sets
// x 4 rows x 16 o) -> DS pipe (48 cyc) well under VALU (512 SIMD-cyc).
// 4 col-passes of 128 cols; acc[2][4][16] = 128 VGPRs.
// __launch_bounds__(512,1): 256-VGPR budget -> no scratch spill (the (512,2)
// bound pinned VGPR at 128 and spilled ~300 MB each way; LDS=137 KB allows
// only 1 block/CU regardless, so the tighter bound bought nothing).
// i-loop kept rolled: hot body ~10 KB (I-cache safe); all arrays
// statically indexed inside. Accumulation order (i, dy, dx) per output
// identical to previous rounds -> bit-identical result.
__global__ __launch_bounds__(512, 1)
void final_kernel(const float* __restrict__ v, const float* __restrict__ weT,
                  const float* __restrict__ br, float* __restrict__ out){
  __shared__ float vt[CMS][6][520];             // rows r0-1..r0+4, col+1 shift
  __shared__ __align__(16) float wl[K72*CHS];   // 36,864 B  [k][o]
  __shared__ float brs[CHS];
  int band = blockIdx.x, n = blockIdx.y;
  int tid = threadIdx.x;
  int r0 = band*4;
  for (int l = tid; l < CMS*6*512; l += 512){
    int i = l / 3072, rem = l - i*3072, r = rem >> 9, x = rem & 511;
    int gy = r0 - 1 + r;
    float val = 0.f;
    if ((unsigned)gy < HW) val = v[((n*CMS+i)*HW + gy)*HW + x];
    vt[i][r][x+1] = val;
  }
  if (tid < CMS*6){ int i = tid/6, r = tid - i*6; vt[i][r][0] = 0.f; vt[i][r][513] = 0.f; }
  for (int l = tid; l < K72*CHS; l += 512) wl[l] = weT[n*K72*CHS + l];
  if (tid < CHS) brs[tid] = br[tid];
  __syncthreads();
  int wid = __builtin_amdgcn_readfirstlane(tid >> 6);  // wave id = o-chunk
  int lane = tid & 63;
  int ob = wid * 16;
  for (int cp = 0; cp < 4; cp++){
    int colA = cp*128 + lane;
    int colB = colA + 64;
    float accA[4][16], accB[4][16];
    #pragma unroll
    for (int rr = 0; rr < 4; rr++)
      #pragma unroll
      for (int j = 0; j < 16; j++){ accA[rr][j] = 0.f; accB[rr][j] = 0.f; }
    for (int i = 0; i < 8; i++){
      float vA[6][3], vB[6][3];
      #pragma unroll
      for (int r = 0; r < 6; r++){
        #pragma unroll
        for (int dc = 0; dc < 3; dc++){
          vA[r][dc] = vt[i][r][colA + dc];
          vB[r][dc] = vt[i][r][colB + dc];
        }
      }
      #pragma unroll
      for (int dy = 0; dy < 3; dy++){
        #pragma unroll
        for (int dx = 0; dx < 3; dx++){
          const float4* wp = (const float4*)&wl[(i*9 + dy*3 + dx)*CHS + ob];
          float4 w0 = wp[0], w1 = wp[1], w2 = wp[2], w3 = wp[3];
          #pragma unroll
          for (int rr = 0; rr < 4; rr++){
            float va = vA[rr + dy][dx];
            accA[rr][0]  += w0.x*va; accA[rr][1]  += w0.y*va; accA[rr][2]  += w0.z*va; accA[rr][3]  += w0.w*va;
            accA[rr][4]  += w1.x*va; accA[rr][5]  += w1.y*va; accA[rr][6]  += w1.z*va; accA[rr][7]  += w1.w*va;
            accA[rr][8]  += w2.x*va; accA[rr][9]  += w2.y*va; accA[rr][10] += w2.z*va; accA[rr][11] += w2.w*va;
            accA[rr][12] += w3.x*va; accA[rr][13] += w3.y*va; accA[rr][14] += w3.z*va; accA[rr][15] += w3.w*va;
            float vb = vB[rr + dy][dx];
            accB[rr][0]  += w0.x*vb; accB[rr][1]  += w0.y*vb; accB[rr][2]  += w0.z*vb; accB[rr][3]  += w0.w*vb;
            accB[rr][4]  += w1.x*vb; accB[rr][5]  += w1.y*vb; accB[rr][6]  += w1.z*vb; accB[rr][7]  += w1.w*vb;
            accB[rr][8]  += w2.x*vb; accB[rr][9]  += w2.y*vb; accB[rr][10] += w2.z*vb; accB[rr][11] += w2.w*vb;
            accB[rr][12] += w3.x*vb; accB[rr][13] += w3.y*vb; accB[rr][14] += w3.z*vb; accB[rr][15] += w3.w*vb;
          }
        }
      }
    }
    #pragma unroll
    for (int j = 0; j < 16; j++){
      int o = ob + j;
      float bb = brs[o];
      #pragma unroll
      for (int rr = 0; rr < 4; rr++){
        int rowbase = ((n*CHS + o)*HW + (r0 + rr))*HW;
        out[rowbase + colA] = lrelu(accA[rr][j] + bb);
        out[rowbase + colB] = lrelu(accB[rr][j] + bb);
      }
    }
  }
}

extern "C" void kernel_launch(void* const* d_in, const int* in_sizes, int n_in,
                              void* d_out, int out_size, void* d_ws, size_t ws_size,
                              hipStream_t stream){
  const float* hrms = (const float*)d_in[0];
  const float* msi  = (const float*)d_in[1];
  const float* hsi  = (const float*)d_in[2];
  const float* Wv   = (const float*)d_in[3];
  const float* bv   = (const float*)d_in[4];
  const float* Wq   = (const float*)d_in[5];
  const float* bq   = (const float*)d_in[6];
  const float* Wk   = (const float*)d_in[7];
  const float* bk   = (const float*)d_in[8];
  const float* Wr   = (const float*)d_in[9];
  const float* br   = (const float*)d_in[10];
  float* ws = (float*)d_ws;
  float* out = (float*)d_out;

  float* v   = ws + OFF_V;
  float* q   = ws + OFF_Q;
  float* kw  = ws + OFF_K;
  float* bn  = ws + OFF_BN;
  float* ar  = ws + OFF_AR;
  float* a2  = ws + OFF_A2;
  float* weT = ws + OFF_WE;
  float* wkt = ws + OFF_WKT;
  float* wvT = ws + OFF_WVT;

  hipLaunchKernelGGL(prep_kernel, dim3(579), dim3(256), 0, stream, Wk, Wv, wkt, wvT);
  hipLaunchKernelGGL(conv_v_kernel, dim3(16,16,2), dim3(256), 0, stream, hrms, wvT, bv, v);
  hipLaunchKernelGGL(conv_q_kernel, dim3(64), dim3(256), 0, stream, msi, Wq, bq, q);
  hipLaunchKernelGGL(bandnorm_kernel, dim3(16), dim3(256), 0, stream, q, bn);
  hipLaunchKernelGGL(conv_k_kernel, dim3(8,32,2), dim3(128), 0, stream, hsi, wkt, bk, kw);
  hipLaunchKernelGGL(att_kernel, dim3(256), dim3(128), 0, stream, q, kw, bn, ar);
  hipLaunchKernelGGL(softmax_kernel, dim3(16), dim3(128), 0, stream, ar, a2);
  hipLaunchKernelGGL(weff_kernel, dim3(256), dim3(128), 0, stream, Wr, a2, weT);
  hipLaunchKernelGGL(final_kernel, dim3(128, 2), dim3(512), 0, stream, v, weT, br, out);
}

// Round 5
// 522.100 us; speedup vs baseline: 2.9436x; 1.1319x over previous
//
#include <hip/hip_runtime.h>
#include <hip/hip_bf16.h>

#define LK 0.01f
__device__ __forceinline__ float lrelu(float x){ return x >= 0.f ? x : LK * x; }

// Problem dims
#define NB 2
#define CMS 8       // band_ms
#define CHS 128     // band_hs
#define HW 512
#define HSIN 128    // hsi spatial
#define OS 32       // q/k spatial
#define K72 72      // 8 ch * 9 taps

// Workspace layout (float offsets).
#define OFF_V   0                        // v fp32 (UNUSED after fusion; kept for layout stability)
#define SZ_V    (NB*CMS*HW*HW)
#define OFF_Q   (OFF_V + SZ_V)           // q fp32 [2][8][32][32]
#define SZ_Q    (NB*CMS*OS*OS)
#define OFF_K   (OFF_Q + SZ_Q)           // k fp32 [2][128][32][32]
#define SZ_K    (NB*CHS*OS*OS)
#define OFF_BN  (OFF_K + SZ_K)           // band norms [16] (pad 64)
#define OFF_AR  (OFF_BN + 64)            // att raw [2][8][128]
#define SZ_AR   (NB*CMS*CHS)
#define OFF_A2  (OFF_AR + SZ_AR)         // att softmaxed/6 [2][8][128]
#define OFF_WE  (OFF_A2 + SZ_AR)         // WeffT fp32 [n][72][128]
#define SZ_WE   (NB*K72*CHS)
#define OFF_WKT (OFF_WE + SZ_WE)         // Wk transposed fp32 [1152][128]
#define SZ_WKT  (1152*CHS)
#define OFF_WVT (OFF_WKT + SZ_WKT)       // Wv transposed fp32 [72][8]
#define SZ_WVT  (K72*CMS)

// ---------------- prep: transpose Wk (64x64 LDS tiles, coalesced both sides)
// and Wv to k-major. Grid (18, 2), 256 threads.
__global__ void prep_kernel(const float* __restrict__ Wk, const float* __restrict__ Wv,
                            float* __restrict__ wkt, float* __restrict__ wvT){
  __shared__ float t[64][65];
  int bx = blockIdx.x, by = blockIdx.y;          // kk-tile, co-tile
  int tx = threadIdx.x & 63, ty = threadIdx.x >> 6;
  #pragma unroll
  for (int r = ty; r < 64; r += 4)               // r = co within tile
    t[r][tx] = Wk[(by*64 + r)*1152 + bx*64 + tx];
  __syncthreads();
  #pragma unroll
  for (int r = ty; r < 64; r += 4)               // r = kk within tile
    wkt[(bx*64 + r)*128 + by*64 + tx] = t[tx][r];
  if (bx == 0 && by == 0){
    for (int l = threadIdx.x; l < 576; l += 256){
      int co = l & 7, kt = l >> 3;
      wvT[kt*8 + co] = Wv[co*72 + kt];
    }
  }
}

// ---------------- conv_q: 3x3 stride 16 p1, 8->8, lrelu ----------------
__global__ void conv_q_kernel(const float* __restrict__ msi, const float* __restrict__ Wq,
                              const float* __restrict__ bq, float* __restrict__ q){
  __shared__ float rows[CMS][3][512];
  __shared__ float wq[K72*CMS];
  __shared__ float bqs[CMS];
  int n = blockIdx.x >> 5, y = blockIdx.x & 31;
  int tid = threadIdx.x;
  int y0 = y*16 - 1;
  for (int l = tid; l < CMS*3*512; l += 256){
    int ci = l / 1536, r = l % 1536, rr = r >> 9, xx = r & 511;
    int gy = y0 + rr;
    float val = 0.f;
    if ((unsigned)gy < HW) val = msi[((n*CMS+ci)*HW + gy)*HW + xx];
    rows[ci][rr][xx] = val;
  }
  for (int l = tid; l < K72*CMS; l += 256) wq[l] = Wq[l];   // [co][ci*9+tap]
  if (tid < CMS) bqs[tid] = bq[tid];
  __syncthreads();
  int x = tid & 31, co = tid >> 5;
  int x0 = x*16 - 1;
  float acc = bqs[co];
  #pragma unroll
  for (int ci = 0; ci < 8; ci++){
    #pragma unroll
    for (int tap = 0; tap < 9; tap++){
      int xi = x0 + tap%3;
      float vv = ((unsigned)xi < HW) ? rows[ci][tap/3][xi] : 0.f;
      acc += vv * wq[co*72 + ci*9 + tap];
    }
  }
  q[((n*CMS+co)*OS + y)*OS + x] = lrelu(acc);
}

// ---------------- per-band L2 norms of q ----------------
__global__ void bandnorm_kernel(const float* __restrict__ q, float* __restrict__ bn){
  int b = blockIdx.x;                 // n*8+i, 16 blocks
  int tid = threadIdx.x;              // 256
  const float* qb = q + b*1024;
  float s = 0.f;
  for (int j = tid; j < 1024; j += 256){ float v = qb[j]; s += v*v; }
  __shared__ float red[4];
  for (int off = 32; off; off >>= 1) s += __shfl_down(s, off);
  if ((tid & 63) == 0) red[tid >> 6] = s;
  __syncthreads();
  if (tid == 0) bn[b] = sqrtf(red[0] + red[1] + red[2] + red[3]);
}

// ---------------- conv_k: 3x3 stride 4 p1, 128->128, lrelu ----------------
__global__ void conv_k_kernel(const float* __restrict__ hsi, const float* __restrict__ wkt,
                              const float* __restrict__ bk, float* __restrict__ kw){
  __shared__ __align__(16) float patch[1152][4];
  int xg = blockIdx.x, y = blockIdx.y, n = blockIdx.z;
  int tid = threadIdx.x;
  for (int l = tid; l < 4608; l += 128){
    int kk = l >> 2, xi = l & 3;
    int ci = kk / 9, tap = kk % 9;
    int gy = 4*y + tap/3 - 1, gx = 4*(xg*4 + xi) + tap%3 - 1;
    float val = 0.f;
    if ((unsigned)gy < HSIN && (unsigned)gx < HSIN)
      val = hsi[((n*CHS+ci)*HSIN + gy)*HSIN + gx];
    patch[kk][xi] = val;
  }
  __syncthreads();
  int co = tid;
  float bkv = bk[co];
  float a0 = bkv, a1 = bkv, a2 = bkv, a3 = bkv;
  #pragma unroll 8
  for (int kk = 0; kk < 1152; kk++){
    float4 p = *(const float4*)patch[kk];   // broadcast b128
    float w = wkt[kk*128 + co];             // coalesced, L2-hot
    a0 += p.x * w; a1 += p.y * w; a2 += p.z * w; a3 += p.w * w;
  }
  int base = ((n*CHS + co)*OS + y)*OS + xg*4;
  kw[base + 0] = lrelu(a0); kw[base + 1] = lrelu(a1);
  kw[base + 2] = lrelu(a2); kw[base + 3] = lrelu(a3);
}

// ---------------- attention scores: ar[n,i,c] = <q_i, k_c>/k0max ----------------
__global__ void att_kernel(const float* __restrict__ q, const float* __restrict__ kw,
                           const float* __restrict__ bn, float* __restrict__ ar){
  int n = blockIdx.x >> 7, c = blockIdx.x & 127;
  int tid = threadIdx.x;   // 128
  const float* kb = kw + (n*CHS + c)*1024;
  float kreg[8];
  #pragma unroll
  for (int u = 0; u < 8; u++) kreg[u] = kb[tid + u*128];
  float m = bn[n*8];
  #pragma unroll
  for (int i = 1; i < 8; i++) m = fmaxf(m, bn[n*8 + i]);
  __shared__ float red[2];
  for (int i = 0; i < 8; i++){
    const float* qb = q + (n*CMS + i)*1024;
    float s = 0.f;
    #pragma unroll
    for (int u = 0; u < 8; u++) s += qb[tid + u*128] * kreg[u];
    for (int off = 32; off; off >>= 1) s += __shfl_down(s, off);
    if ((tid & 63) == 0) red[tid >> 6] = s;
    __syncthreads();
    if (tid == 0) ar[(n*CMS + i)*CHS + c] = (red[0] + red[1]) / m;
    __syncthreads();
  }
}

// ---------------- softmax over c (scale 10), then /6 ----------------
__global__ void softmax_kernel(const float* __restrict__ ar, float* __restrict__ a2){
  int b = blockIdx.x;      // n*8+i, 16 blocks
  int tid = threadIdx.x;   // 128 = c
  float x = ar[b*128 + tid] * 10.f;
  __shared__ float red[2];
  float m = x;
  for (int off = 32; off; off >>= 1) m = fmaxf(m, __shfl_xor(m, off));
  if ((tid & 63) == 0) red[tid >> 6] = m;
  __syncthreads();
  m = fmaxf(red[0], red[1]);
  float e = expf(x - m);
  float s = e;
  for (int off = 32; off; off >>= 1) s += __shfl_xor(s, off);
  __syncthreads();
  if ((tid & 63) == 0) red[tid >> 6] = s;
  __syncthreads();
  s = red[0] + red[1];
  a2[b*128 + tid] = e / (6.f * s);
}

// ---------------- Weff: weT[n][i*9+tap][o] = sum_c Wr[o,c,tap]*a2[n,i,c] ----------------
__global__ void weff_kernel(const float* __restrict__ Wr, const float* __restrict__ a2,
                            float* __restrict__ weT){
  int o = blockIdx.x & 127, n = blockIdx.x >> 7;
  int t = threadIdx.x;     // 128, first 72 active
  if (t >= 72) return;
  int i = t / 9, tap = t % 9;
  const float* av = a2 + (n*CMS + i)*CHS;
  float s = 0.f;
  for (int c = 0; c < 128; c++)
    s += Wr[(o*128 + c)*9 + tap] * av[c];
  weT[(n*K72 + t)*CHS + o] = s;
}

// ---------------- fused final: conv_v (phase 1) + attention-mixed conv (phase 2) ----
// Block = (band of 4 out rows, n), grid 256 = 1 block/CU, 512 threads (8 waves).
// PHASE 1 computes the v-tile (6 rows x 512 x 8ch) in-block: thread=col,
// acc_v[6][8] in regs; hrms staged ci-by-ci into a 16.6 KB LDS buffer with
// register-prefetch of ci+1 hidden under compute. Weight (ci,tap) blocks read
// once and reused across 6 rows (4x fewer LDS weight reads than the old
// standalone conv_v). v values use conv_v's exact FMA order (ci, then tap
// ascending), bias+lrelu at the end -> bit-identical v, and the global
// v round-trip (16.8 MB write + 25 MB read) + one launch are eliminated.
// PHASE 2 identical to round-3's verified kernel (wave owns one 16-o chunk,
// 4 col-passes, acc[2][4][16]).
// LDS: vt 99.8K + wl 36.9K + hbuf 16.6K + wv/br/bv ~2.9K = ~156 KB (<160).
__global__ __launch_bounds__(512, 1)
void final_kernel(const float* __restrict__ hrms, const float* __restrict__ wvT,
                  const float* __restrict__ bv, const float* __restrict__ weT,
                  const float* __restrict__ br, float* __restrict__ out){
  __shared__ float vt[CMS][6][520];             // v rows r0-1..r0+4, col+1 shift
  __shared__ __align__(16) float wl[K72*CHS];   // 36,864 B  [k][o]
  __shared__ float hbuf[8][520];                // hrms rows r0-2..r0+5, one ci
  __shared__ __align__(16) float wvs[K72*CMS];  // conv_v weights [k][co]
  __shared__ float brs[CHS];
  __shared__ float bvs[CMS];
  int band = blockIdx.x, n = blockIdx.y;
  int tid = threadIdx.x;
  int r0 = band*4;
  // --- stage weights / biases / vt edge zeros ---
  for (int l = tid; l < K72*CHS; l += 512) wl[l] = weT[n*K72*CHS + l];
  for (int l = tid; l < K72*CMS; l += 512) wvs[l] = wvT[l];
  if (tid < CHS) brs[tid] = br[tid];
  if (tid < CMS) bvs[tid] = bv[tid];
  if (tid < CMS*6){ int i = tid/6, r = tid - i*6; vt[i][r][0] = 0.f; vt[i][r][513] = 0.f; }

  // ---------------- phase 1: compute v tile ----------------
  int col = tid;                                 // 0..511
  float acc_v[6][8];
  #pragma unroll
  for (int r = 0; r < 6; r++)
    #pragma unroll
    for (int c = 0; c < 8; c++) acc_v[r][c] = 0.f;

  float stg[9];
  {
    const float* hp = hrms + (size_t)(n*CMS + 0)*HW*HW;
    #pragma unroll
    for (int u = 0; u < 9; u++){
      int l = tid + u*512;
      float val = 0.f;
      if (l < 4112){
        int row = l / 514, cc = l - row*514;
        int gy = r0 - 2 + row, gx = cc - 1;
        if ((unsigned)gy < HW && (unsigned)gx < HW) val = hp[gy*HW + gx];
      }
      stg[u] = val;
    }
  }
  for (int ci = 0; ci < 8; ci++){
    __syncthreads();                             // hbuf free (prev compute done)
    #pragma unroll
    for (int u = 0; u < 9; u++){
      int l = tid + u*512;
      if (l < 4112){ int row = l / 514, cc = l - row*514; hbuf[row][cc] = stg[u]; }
    }
    __syncthreads();                             // hbuf ready
    if (ci < 7){
      const float* hp = hrms + (size_t)(n*CMS + ci + 1)*HW*HW;
      #pragma unroll
      for (int u = 0; u < 9; u++){
        int l = tid + u*512;
        float val = 0.f;
        if (l < 4112){
          int row = l / 514, cc = l - row*514;
          int gy = r0 - 2 + row, gx = cc - 1;
          if ((unsigned)gy < HW && (unsigned)gx < HW) val = hp[gy*HW + gx];
        }
        stg[u] = val;
      }
    }
    #pragma unroll
    for (int tap = 0; tap < 9; tap++){
      const float4* wp = (const float4*)&wvs[(ci*9 + tap)*8];
      float4 w0 = wp[0], w1 = wp[1];
      int dy = tap/3, dx = tap%3;
      #pragma unroll
      for (int r = 0; r < 6; r++){
        float hb = hbuf[r + dy][col + dx];
        acc_v[r][0] += w0.x*hb; acc_v[r][1] += w0.y*hb; acc_v[r][2] += w0.z*hb; acc_v[r][3] += w0.w*hb;
        acc_v[r][4] += w1.x*hb; acc_v[r][5] += w1.y*hb; acc_v[r][6] += w1.z*hb; acc_v[r][7] += w1.w*hb;
      }
    }
  }
  #pragma unroll
  for (int r = 0; r < 6; r++){
    int gy = r0 - 1 + r;
    bool ok = (unsigned)gy < HW;
    #pragma unroll
    for (int c = 0; c < 8; c++){
      float t = acc_v[r][c] + bvs[c];
      vt[c][r][col + 1] = ok ? (t >= 0.f ? t : LK*t) : 0.f;
    }
  }
  __syncthreads();

  // ---------------- phase 2: attention-mixed 3x3 conv (unchanged) ----------------
  int wid = __builtin_amdgcn_readfirstlane(tid >> 6);  // wave id = o-chunk
  int lane = tid & 63;
  int ob = wid * 16;
  for (int cp = 0; cp < 4; cp++){
    int colA = cp*128 + lane;
    int colB = colA + 64;
    float accA[4][16], accB[4][16];
    #pragma unroll
    for (int rr = 0; rr < 4; rr++)
      #pragma unroll
      for (int j = 0; j < 16; j++){ accA[rr][j] = 0.f; accB[rr][j] = 0.f; }
    for (int i = 0; i < 8; i++){
      float vA[6][3], vB[6][3];
      #pragma unroll
      for (int r = 0; r < 6; r++){
        #pragma unroll
        for (int dc = 0; dc < 3; dc++){
          vA[r][dc] = vt[i][r][colA + dc];
          vB[r][dc] = vt[i][r][colB + dc];
        }
      }
      #pragma unroll
      for (int dy = 0; dy < 3; dy++){
        #pragma unroll
        for (int dx = 0; dx < 3; dx++){
          const float4* wp = (const float4*)&wl[(i*9 + dy*3 + dx)*CHS + ob];
          float4 w0 = wp[0], w1 = wp[1], w2 = wp[2], w3 = wp[3];
          #pragma unroll
          for (int rr = 0; rr < 4; rr++){
            float va = vA[rr + dy][dx];
            accA[rr][0]  += w0.x*va; accA[rr][1]  += w0.y*va; accA[rr][2]  += w0.z*va; accA[rr][3]  += w0.w*va;
            accA[rr][4]  += w1.x*va; accA[rr][5]  += w1.y*va; accA[rr][6]  += w1.z*va; accA[rr][7]  += w1.w*va;
            accA[rr][8]  += w2.x*va; accA[rr][9]  += w2.y*va; accA[rr][10] += w2.z*va; accA[rr][11] += w2.w*va;
            accA[rr][12] += w3.x*va; accA[rr][13] += w3.y*va; accA[rr][14] += w3.z*va; accA[rr][15] += w3.w*va;
            float vb = vB[rr + dy][dx];
            accB[rr][0]  += w0.x*vb; accB[rr][1]  += w0.y*vb; accB[rr][2]  += w0.z*vb; accB[rr][3]  += w0.w*vb;
            accB[rr][4]  += w1.x*vb; accB[rr][5]  += w1.y*vb; accB[rr][6]  += w1.z*vb; accB[rr][7]  += w1.w*vb;
            accB[rr][8]  += w2.x*vb; accB[rr][9]  += w2.y*vb; accB[rr][10] += w2.z*vb; accB[rr][11] += w2.w*vb;
            accB[rr][12] += w3.x*vb; accB[rr][13] += w3.y*vb; accB[rr][14] += w3.z*vb; accB[rr][15] += w3.w*vb;
          }
        }
      }
    }
    #pragma unroll
    for (int j = 0; j < 16; j++){
      int o = ob + j;
      float bb = brs[o];
      #pragma unroll
      for (int rr = 0; rr < 4; rr++){
        int rowbase = ((n*CHS + o)*HW + (r0 + rr))*HW;
        out[rowbase + colA] = lrelu(accA[rr][j] + bb);
        out[rowbase + colB] = lrelu(accB[rr][j] + bb);
      }
    }
  }
}

extern "C" void kernel_launch(void* const* d_in, const int* in_sizes, int n_in,
                              void* d_out, int out_size, void* d_ws, size_t ws_size,
                              hipStream_t stream){
  const float* hrms = (const float*)d_in[0];
  const float* msi  = (const float*)d_in[1];
  const float* hsi  = (const float*)d_in[2];
  const float* Wv   = (const float*)d_in[3];
  const float* bv   = (const float*)d_in[4];
  const float* Wq   = (const float*)d_in[5];
  const float* bq   = (const float*)d_in[6];
  const float* Wk   = (const float*)d_in[7];
  const float* bk   = (const float*)d_in[8];
  const float* Wr   = (const float*)d_in[9];
  const float* br   = (const float*)d_in[10];
  float* ws = (float*)d_ws;
  float* out = (float*)d_out;

  float* q   = ws + OFF_Q;
  float* kw  = ws + OFF_K;
  float* bn  = ws + OFF_BN;
  float* ar  = ws + OFF_AR;
  float* a2  = ws + OFF_A2;
  float* weT = ws + OFF_WE;
  float* wkt = ws + OFF_WKT;
  float* wvT = ws + OFF_WVT;

  hipLaunchKernelGGL(prep_kernel, dim3(18, 2), dim3(256), 0, stream, Wk, Wv, wkt, wvT);
  hipLaunchKernelGGL(conv_q_kernel, dim3(64), dim3(256), 0, stream, msi, Wq, bq, q);
  hipLaunchKernelGGL(bandnorm_kernel, dim3(16), dim3(256), 0, stream, q, bn);
  hipLaunchKernelGGL(conv_k_kernel, dim3(8,32,2), dim3(128), 0, stream, hsi, wkt, bk, kw);
  hipLaunchKernelGGL(att_kernel, dim3(256), dim3(128), 0, stream, q, kw, bn, ar);
  hipLaunchKernelGGL(softmax_kernel, dim3(16), dim3(128), 0, stream, ar, a2);
  hipLaunchKernelGGL(weff_kernel, dim3(256), dim3(128), 0, stream, Wr, a2, weT);
  hipLaunchKernelGGL(final_kernel, dim3(128, 2), dim3(512), 0, stream,
                     hrms, wvT, bv, weT, br, out);
}